// Round 5
// baseline (235.995 us; speedup 1.0000x reference)
//
#include <hip/hip_runtime.h>
#include <math.h>

#define D 512
#define TEMP_INV 14.285714285714286f  // 1/0.07
#define NBT 64                         // 4096 / 64 tile grid dim
#define NBLK (NBT * (NBT + 1) / 2)     // 2080 upper-tri tiles
#define LROW 72                        // 64 k-elems + 8 pad (16B-aligned rows, bank-balanced)

typedef __bf16 bf16x8 __attribute__((ext_vector_type(8)));
typedef float f32x16 __attribute__((ext_vector_type(16)));

// ws layout (float units):
//   [0]              neg_sum accumulator (float atomic)
//   [1]              completion counter (int atomic)
//   [64 .. 64+2048)  p values (positive-pair logits)
//   [4096 .. )       ebf: normalized bf16 matrix [4096][512] (4 MB), 16B aligned

// One wave per row: compute rsqrt(sum sq), scale, RNE-cast to bf16.
__global__ void infonce_norm_cast_kernel(const float* __restrict__ emb,
                                         float* __restrict__ ws, int nrows) {
    if (blockIdx.x == 0 && threadIdx.x == 0) {
        ws[0] = 0.0f;             // neg_sum
        ((int*)ws)[1] = 0;        // completion counter
    }
    unsigned short* __restrict__ ebf = (unsigned short*)(ws + 4096);
    const int lane = threadIdx.x & 63;
    const int wave = threadIdx.x >> 6;
    const int row = blockIdx.x * 4 + wave;
    if (row >= nrows) return;
    const float* r = emb + (size_t)row * D;
    float4 v1 = *(const float4*)&r[lane * 4];
    float4 v2 = *(const float4*)&r[256 + lane * 4];
    float s = v1.x * v1.x + v1.y * v1.y + v1.z * v1.z + v1.w * v1.w
            + v2.x * v2.x + v2.y * v2.y + v2.z * v2.z + v2.w * v2.w;
    #pragma unroll
    for (int off = 32; off > 0; off >>= 1) s += __shfl_down(s, off, 64);
    const float rn = __shfl(rsqrtf(s), 0, 64);

    float f[8] = {v1.x, v1.y, v1.z, v1.w, v2.x, v2.y, v2.z, v2.w};
    unsigned short h[8];
    #pragma unroll
    for (int e = 0; e < 8; ++e) {
        unsigned int u = __float_as_uint(f[e] * rn);
        h[e] = (unsigned short)((u + 0x7FFFu + ((u >> 16) & 1u)) >> 16);  // RNE
    }
    ushort4* dst1 = (ushort4*)&ebf[(size_t)row * D + lane * 4];
    ushort4* dst2 = (ushort4*)&ebf[(size_t)row * D + 256 + lane * 4];
    *dst1 = make_ushort4(h[0], h[1], h[2], h[3]);
    *dst2 = make_ushort4(h[4], h[5], h[6], h[7]);
}

// Upper-triangular 64x64 tiles (2080 blocks -> 4 blocks/CU, 16 waves/CU),
// 256 threads (4 waves). Wave w -> 32x32 quadrant (wy,wx) via
// mfma_f32_32x32x16_bf16 (one f32x16 accumulator). BK=64 (4 K-chunks of 16),
// rotating LDS double-buffer, ONE barrier/iter, depth-1 register prefetch:
// next chunk's loads issued right after the barrier, stored after compute.
// Loss fused via last-block completion counter.
__global__ __launch_bounds__(256, 4) void infonce_sim_kernel(
        const int* __restrict__ labels, float* __restrict__ ws,
        float* __restrict__ out) {
    // contiguous-per-XCD chunking (2080 % 8 == 0)
    const int grp = gridDim.x >> 3;
    const int tile = (blockIdx.x & 7) * grp + (blockIdx.x >> 3);
    // triangular decode: row-major over {(bi,bj): bj>=bi}
    int rem = tile, bi = 0;
    while (rem >= (NBT - bi)) { rem -= (NBT - bi); ++bi; }
    const int bj = bi + rem;

    const unsigned short* __restrict__ ebf = (const unsigned short*)(ws + 4096);
    float* __restrict__ pvals = ws + 64;

    __shared__ unsigned short As[2][64 * LROW];  // 9216 B each
    __shared__ unsigned short Bs[2][64 * LROW];
    __shared__ int lab_row[64], lab_col[64];
    __shared__ float red[4];
    __shared__ int is_last;

    const int t = threadIdx.x;
    const int w = t >> 6, l = t & 63;
    const int wy = w >> 1, wx = w & 1;
    const int ln = l & 31;       // n/m index within 32x32 tile
    const int hi = l >> 5;       // k-half selector
    const int rowA0 = bi * 64, rowB0 = bj * 64;

    if (t < 64) lab_row[t] = labels[(rowA0 + t) >> 1];
    else if (t < 128) lab_col[t - 64] = labels[(rowB0 + t - 64) >> 1];

    // staging: thread t stages A rows {srow, srow+32} and B rows {srow, srow+32},
    // 16B chunk sc (k-offset sc*8) of the current 64-elem K-chunk.
    const int srow = t >> 3, sc = t & 7;
    const unsigned short* gA0 = ebf + ((size_t)(rowA0 + srow) << 9) + sc * 8;
    const unsigned short* gA1 = ebf + ((size_t)(rowA0 + srow + 32) << 9) + sc * 8;
    const unsigned short* gB0 = ebf + ((size_t)(rowB0 + srow) << 9) + sc * 8;
    const unsigned short* gB1 = ebf + ((size_t)(rowB0 + srow + 32) << 9) + sc * 8;
    const int lofs0 = srow * LROW + sc * 8;
    const int lofs1 = lofs0 + 32 * LROW;

    f32x16 acc = {};

    // prologue: K-chunk 0 into buffer 0
    {
        uint4 pa0 = *(const uint4*)gA0;
        uint4 pa1 = *(const uint4*)gA1;
        uint4 pb0 = *(const uint4*)gB0;
        uint4 pb1 = *(const uint4*)gB1;
        *(uint4*)&As[0][lofs0] = pa0;
        *(uint4*)&As[0][lofs1] = pa1;
        *(uint4*)&Bs[0][lofs0] = pb0;
        *(uint4*)&Bs[0][lofs1] = pb1;
    }

    #pragma unroll
    for (int it = 0; it < 8; ++it) {
        const int cur = it & 1;
        __syncthreads();  // publishes buffer `cur` (stored in prev iter)
        uint4 pa0, pa1, pb0, pb1;
        if (it < 7) {  // issue next K-chunk's loads; land during compute
            const int k0 = (it + 1) * 64;
            pa0 = *(const uint4*)(gA0 + k0);
            pa1 = *(const uint4*)(gA1 + k0);
            pb0 = *(const uint4*)(gB0 + k0);
            pb1 = *(const uint4*)(gB1 + k0);
        }
        #pragma unroll
        for (int kc = 0; kc < 4; ++kc) {
            const bf16x8 af = *(const bf16x8*)&As[cur][(wy * 32 + ln) * LROW + kc * 16 + hi * 8];
            const bf16x8 bf = *(const bf16x8*)&Bs[cur][(wx * 32 + ln) * LROW + kc * 16 + hi * 8];
            acc = __builtin_amdgcn_mfma_f32_32x32x16_bf16(af, bf, acc, 0, 0, 0);
        }
        if (it < 7) {  // store into the other buffer; safe: one barrier/iter
            const int nxt = cur ^ 1;
            *(uint4*)&As[nxt][lofs0] = pa0;
            *(uint4*)&As[nxt][lofs1] = pa1;
            *(uint4*)&Bs[nxt][lofs0] = pb0;
            *(uint4*)&Bs[nxt][lofs1] = pb1;
        }
    }

    // Epilogue: 32x32 C/D layout: col = lane&31, row = (reg&3)+8*(reg>>2)+4*(lane>>5).
    float neg_local = 0.0f;
    #pragma unroll
    for (int reg = 0; reg < 16; ++reg) {
        const int rrow = (reg & 3) + 8 * (reg >> 2) + 4 * hi;
        const int li = wy * 32 + rrow;
        const int lj = wx * 32 + ln;
        const int i = rowA0 + li;
        const int j = rowB0 + lj;
        const float S = acc[reg] * TEMP_INV;
        if (j > i) {
            if (lab_row[li] != lab_col[lj]) neg_local += __expf(S);
            if (!(i & 1) && j == i + 1) pvals[i >> 1] = S;
        }
    }

    float s = neg_local;
    #pragma unroll
    for (int off = 32; off > 0; off >>= 1) s += __shfl_down(s, off, 64);
    if (l == 0) red[w] = s;
    __syncthreads();
    if (t == 0) atomicAdd(ws, red[0] + red[1] + red[2] + red[3]);

    // ---- fused loss: last block to finish reduces the 2048 pairs ----
    __threadfence();  // release: pvals stores + neg atomic visible device-wide
    if (t == 0) {
        const int prev = atomicAdd((int*)ws + 1, 1);
        is_last = (prev == NBLK - 1);
    }
    __syncthreads();
    if (!is_last) return;
    __threadfence();  // acquire

    const float neg = __hip_atomic_load(ws, __ATOMIC_RELAXED, __HIP_MEMORY_SCOPE_AGENT);
    const volatile float* __restrict__ pv = ws + 64;
    float local = 0.0f;
    for (int k = t; k < 2048; k += 256) {
        const float p = pv[k];
        local += logf(__expf(p) + neg) - p;
    }
    float ls = local;
    #pragma unroll
    for (int off = 32; off > 0; off >>= 1) ls += __shfl_down(ls, off, 64);
    if (l == 0) red[w] = ls;
    __syncthreads();
    if (t == 0) out[0] = (red[0] + red[1] + red[2] + red[3]) / 2048.0f;
}

extern "C" void kernel_launch(void* const* d_in, const int* in_sizes, int n_in,
                              void* d_out, int out_size, void* d_ws, size_t ws_size,
                              hipStream_t stream) {
    const float* emb = (const float*)d_in[0];
    const int* labels = (const int*)d_in[1];
    float* out = (float*)d_out;
    float* ws = (float*)d_ws;

    const int ntot = in_sizes[0] / D;  // 4096

    infonce_norm_cast_kernel<<<ntot / 4, 256, 0, stream>>>(emb, ws, ntot);
    infonce_sim_kernel<<<NBLK, 256, 0, stream>>>(labels, ws, out);
}

// Round 6
// 139.991 us; speedup vs baseline: 1.6858x; 1.6858x over previous
//
#include <hip/hip_runtime.h>
#include <math.h>

#define D 512
#define TEMP_INV 14.285714285714286f  // 1/0.07
#define NBT 64                         // 4096 / 64 tile grid dim
#define NBLK (NBT * (NBT + 1) / 2)     // 2080 upper-tri tiles
#define LROW 72                        // 64 k-elems + 8 pad (16B-aligned rows)

typedef __bf16 bf16x8 __attribute__((ext_vector_type(8)));
typedef float f32x16 __attribute__((ext_vector_type(16)));

// ws layout (float units):
//   [0]              neg_sum accumulator (float atomic)
//   [64 .. 64+2048)  p values (positive-pair logits)
//   [4096 .. )       ebf: normalized bf16 matrix [4096][512] (4 MB), 16B aligned

// One wave per row: compute rsqrt(sum sq), scale, RNE-cast to bf16.
__global__ void infonce_norm_cast_kernel(const float* __restrict__ emb,
                                         float* __restrict__ ws, int nrows) {
    if (blockIdx.x == 0 && threadIdx.x == 0) ws[0] = 0.0f;  // zero neg_sum
    unsigned short* __restrict__ ebf = (unsigned short*)(ws + 4096);
    const int lane = threadIdx.x & 63;
    const int wave = threadIdx.x >> 6;
    const int row = blockIdx.x * 4 + wave;
    if (row >= nrows) return;
    const float* r = emb + (size_t)row * D;
    float4 v1 = *(const float4*)&r[lane * 4];
    float4 v2 = *(const float4*)&r[256 + lane * 4];
    float s = v1.x * v1.x + v1.y * v1.y + v1.z * v1.z + v1.w * v1.w
            + v2.x * v2.x + v2.y * v2.y + v2.z * v2.z + v2.w * v2.w;
    #pragma unroll
    for (int off = 32; off > 0; off >>= 1) s += __shfl_down(s, off, 64);
    const float rn = __shfl(rsqrtf(s), 0, 64);

    float f[8] = {v1.x, v1.y, v1.z, v1.w, v2.x, v2.y, v2.z, v2.w};
    unsigned short h[8];
    #pragma unroll
    for (int e = 0; e < 8; ++e) {
        unsigned int u = __float_as_uint(f[e] * rn);
        h[e] = (unsigned short)((u + 0x7FFFu + ((u >> 16) & 1u)) >> 16);  // RNE
    }
    ushort4* dst1 = (ushort4*)&ebf[(size_t)row * D + lane * 4];
    ushort4* dst2 = (ushort4*)&ebf[(size_t)row * D + 256 + lane * 4];
    *dst1 = make_ushort4(h[0], h[1], h[2], h[3]);
    *dst2 = make_ushort4(h[4], h[5], h[6], h[7]);
}

// Upper-triangular 64x64 tiles (2080 blocks -> 4 blocks/CU, 16 waves/CU),
// 256 threads (4 waves). Wave w -> 32x32 quadrant (wy,wx) via
// mfma_f32_32x32x16_bf16. BK=64 (4 K-steps of 16), rotating LDS
// double-buffer, ONE barrier/iter, depth-2 register prefetch: K-chunk it+2
// issued at iter it, stored to LDS at end of iter it+1 -> ~2 compute phases
// of latency slack. NO device-scope fences (R5 lesson: L2-invalidate thrash).
__global__ __launch_bounds__(256, 4) void infonce_sim_kernel(
        const int* __restrict__ labels, float* __restrict__ ws) {
    // contiguous-per-XCD chunking (2080 % 8 == 0)
    const int grp = gridDim.x >> 3;
    const int tile = (blockIdx.x & 7) * grp + (blockIdx.x >> 3);
    // triangular decode: row-major over {(bi,bj): bj>=bi}
    int rem = tile, bi = 0;
    while (rem >= (NBT - bi)) { rem -= (NBT - bi); ++bi; }
    const int bj = bi + rem;

    const unsigned short* __restrict__ ebf = (const unsigned short*)(ws + 4096);
    float* __restrict__ pvals = ws + 64;

    __shared__ unsigned short As[2][64 * LROW];  // 9216 B each
    __shared__ unsigned short Bs[2][64 * LROW];
    __shared__ int lab_row[64], lab_col[64];
    __shared__ float red[4];

    const int t = threadIdx.x;
    const int w = t >> 6, l = t & 63;
    const int wy = w >> 1, wx = w & 1;
    const int ln = l & 31;       // m/n index within 32x32 tile
    const int hi = l >> 5;       // k-half selector
    const int rowA0 = bi * 64, rowB0 = bj * 64;

    if (t < 64) lab_row[t] = labels[(rowA0 + t) >> 1];
    else if (t < 128) lab_col[t - 64] = labels[(rowB0 + t - 64) >> 1];

    // staging: thread t stages rows {srow, srow+32}, 16B chunk sc of the
    // current 64-elem K-chunk, for both A and B panels.
    const int srow = t >> 3, sc = t & 7;
    const unsigned short* gA0 = ebf + ((size_t)(rowA0 + srow) << 9) + sc * 8;
    const unsigned short* gA1 = ebf + ((size_t)(rowA0 + srow + 32) << 9) + sc * 8;
    const unsigned short* gB0 = ebf + ((size_t)(rowB0 + srow) << 9) + sc * 8;
    const unsigned short* gB1 = ebf + ((size_t)(rowB0 + srow + 32) << 9) + sc * 8;
    const int lofs0 = srow * LROW + sc * 8;
    const int lofs1 = lofs0 + 32 * LROW;

    f32x16 acc = {};
    uint4 pA[2][2], pB[2][2];  // two prefetch register sets, 2 chunks each

    // prologue: chunk0 -> set0 -> buf0; chunk1 -> set1 (in flight)
    pA[0][0] = *(const uint4*)gA0;  pA[0][1] = *(const uint4*)gA1;
    pB[0][0] = *(const uint4*)gB0;  pB[0][1] = *(const uint4*)gB1;
    *(uint4*)&As[0][lofs0] = pA[0][0];  *(uint4*)&As[0][lofs1] = pA[0][1];
    *(uint4*)&Bs[0][lofs0] = pB[0][0];  *(uint4*)&Bs[0][lofs1] = pB[0][1];
    pA[1][0] = *(const uint4*)(gA0 + 64);  pA[1][1] = *(const uint4*)(gA1 + 64);
    pB[1][0] = *(const uint4*)(gB0 + 64);  pB[1][1] = *(const uint4*)(gB1 + 64);

    #pragma unroll
    for (int it = 0; it < 8; ++it) {
        const int cur = it & 1;
        __syncthreads();  // publishes buffer `cur` (stored end of prev iter)
        if (it < 6) {     // issue K-chunk it+2 into set it&1 (freed last iter)
            const int k0 = (it + 2) * 64;
            pA[cur][0] = *(const uint4*)(gA0 + k0);
            pA[cur][1] = *(const uint4*)(gA1 + k0);
            pB[cur][0] = *(const uint4*)(gB0 + k0);
            pB[cur][1] = *(const uint4*)(gB1 + k0);
        }
        #pragma unroll
        for (int kc = 0; kc < 4; ++kc) {
            const bf16x8 af = *(const bf16x8*)&As[cur][(wy * 32 + ln) * LROW + kc * 16 + hi * 8];
            const bf16x8 bf = *(const bf16x8*)&Bs[cur][(wx * 32 + ln) * LROW + kc * 16 + hi * 8];
            acc = __builtin_amdgcn_mfma_f32_32x32x16_bf16(af, bf, acc, 0, 0, 0);
        }
        if (it < 7) {  // store K-chunk it+1 (set (it+1)&1) into other buffer
            const int nxt = cur ^ 1;
            *(uint4*)&As[nxt][lofs0] = pA[nxt][0];
            *(uint4*)&As[nxt][lofs1] = pA[nxt][1];
            *(uint4*)&Bs[nxt][lofs0] = pB[nxt][0];
            *(uint4*)&Bs[nxt][lofs1] = pB[nxt][1];
        }
    }

    // Epilogue: 32x32 C/D layout: col = lane&31, row = (reg&3)+8*(reg>>2)+4*(lane>>5).
    float neg_local = 0.0f;
    #pragma unroll
    for (int reg = 0; reg < 16; ++reg) {
        const int rrow = (reg & 3) + 8 * (reg >> 2) + 4 * hi;
        const int li = wy * 32 + rrow;
        const int lj = wx * 32 + ln;
        const int i = rowA0 + li;
        const int j = rowB0 + lj;
        const float S = acc[reg] * TEMP_INV;
        if (j > i) {
            if (lab_row[li] != lab_col[lj]) neg_local += __expf(S);
            if (!(i & 1) && j == i + 1) pvals[i >> 1] = S;
        }
    }

    float s = neg_local;
    #pragma unroll
    for (int off = 32; off > 0; off >>= 1) s += __shfl_down(s, off, 64);
    if (l == 0) red[w] = s;
    __syncthreads();
    if (t == 0) atomicAdd(ws, red[0] + red[1] + red[2] + red[3]);
}

__global__ void infonce_loss_kernel(const float* __restrict__ ws,
                                    float* __restrict__ out, int npairs) {
    __shared__ float red[4];
    const float neg = ws[0];
    const float* __restrict__ p = ws + 64;
    float local = 0.0f;
    for (int k = threadIdx.x; k < npairs; k += 256) {
        const float pv = p[k];
        local += logf(__expf(pv) + neg) - pv;
    }
    float s = local;
    #pragma unroll
    for (int off = 32; off > 0; off >>= 1) s += __shfl_down(s, off, 64);
    if ((threadIdx.x & 63) == 0) red[threadIdx.x >> 6] = s;
    __syncthreads();
    if (threadIdx.x == 0)
        out[0] = (red[0] + red[1] + red[2] + red[3]) / (float)npairs;
}

extern "C" void kernel_launch(void* const* d_in, const int* in_sizes, int n_in,
                              void* d_out, int out_size, void* d_ws, size_t ws_size,
                              hipStream_t stream) {
    const float* emb = (const float*)d_in[0];
    const int* labels = (const int*)d_in[1];
    float* out = (float*)d_out;
    float* ws = (float*)d_ws;

    const int ntot = in_sizes[0] / D;  // 4096
    const int npairs = ntot / 2;       // 2048 positive pairs

    infonce_norm_cast_kernel<<<ntot / 4, 256, 0, stream>>>(emb, ws, ntot);
    infonce_sim_kernel<<<NBLK, 256, 0, stream>>>(labels, ws);
    infonce_loss_kernel<<<1, 256, 0, stream>>>(ws, out, npairs);
}

// Round 7
// 105.328 us; speedup vs baseline: 2.2406x; 1.3291x over previous
//
#include <hip/hip_runtime.h>
#include <math.h>

#define D 512
#define TEMP_INV 14.285714285714286f  // 1/0.07
#define NBT 64                         // 4096 / 64 tile grid dim
#define NBLK (NBT * (NBT + 1) / 2)     // 2080 upper-tri tiles

typedef __bf16 bf16x8 __attribute__((ext_vector_type(8)));
typedef float f32x4 __attribute__((ext_vector_type(4)));

// global->LDS direct DMA, 16 B per lane. LDS dest = wave-uniform base + lane*16.
#define GLDS16(g, l) __builtin_amdgcn_global_load_lds(                         \
    (const __attribute__((address_space(1))) unsigned int*)(g),                \
    (__attribute__((address_space(3))) unsigned int*)(l), 16, 0, 0)

// ws layout (float units):
//   [0]              neg_sum accumulator (float atomic)
//   [64 .. 64+2048)  p values (positive-pair logits)
//   [4096 .. )       ebf: normalized bf16 matrix [4096][512] (4 MB), 16B aligned

// One wave per row: compute rsqrt(sum sq), scale, RNE-cast to bf16.
__global__ void infonce_norm_cast_kernel(const float* __restrict__ emb,
                                         float* __restrict__ ws, int nrows) {
    if (blockIdx.x == 0 && threadIdx.x == 0) ws[0] = 0.0f;  // zero neg_sum
    unsigned short* __restrict__ ebf = (unsigned short*)(ws + 4096);
    const int lane = threadIdx.x & 63;
    const int wave = threadIdx.x >> 6;
    const int row = blockIdx.x * 4 + wave;
    if (row >= nrows) return;
    const float* r = emb + (size_t)row * D;
    float4 v1 = *(const float4*)&r[lane * 4];
    float4 v2 = *(const float4*)&r[256 + lane * 4];
    float s = v1.x * v1.x + v1.y * v1.y + v1.z * v1.z + v1.w * v1.w
            + v2.x * v2.x + v2.y * v2.y + v2.z * v2.z + v2.w * v2.w;
    #pragma unroll
    for (int off = 32; off > 0; off >>= 1) s += __shfl_down(s, off, 64);
    const float rn = __shfl(rsqrtf(s), 0, 64);

    float f[8] = {v1.x, v1.y, v1.z, v1.w, v2.x, v2.y, v2.z, v2.w};
    unsigned short h[8];
    #pragma unroll
    for (int e = 0; e < 8; ++e) {
        unsigned int u = __float_as_uint(f[e] * rn);
        h[e] = (unsigned short)((u + 0x7FFFu + ((u >> 16) & 1u)) >> 16);  // RNE
    }
    ushort4* dst1 = (ushort4*)&ebf[(size_t)row * D + lane * 4];
    ushort4* dst2 = (ushort4*)&ebf[(size_t)row * D + 256 + lane * 4];
    *dst1 = make_ushort4(h[0], h[1], h[2], h[3]);
    *dst2 = make_ushort4(h[4], h[5], h[6], h[7]);
}

// Upper-triangular 64x64 tiles (2080 blocks -> 4 blocks/CU, 16 waves/CU),
// 256 threads (4 waves). R3 champion structure: wave w computes rows
// [w*16, w*16+16) x all 64 cols via 16x16x32 bf16 MFMA, acc[4] independent
// chains. BK=64, double-buffered LDS. Staging via global_load_lds (16 B)
// into an UNPADDED XOR-swizzled buffer: slot(row, c) = row*8 + (c ^ (row&7))
// [16B units]. One barrier/iter; glds for chunk it+1 issued right after the
// barrier so its vmcnt(0) drain (at the NEXT barrier) is covered by compute.
__global__ __launch_bounds__(256, 4) void infonce_sim_kernel(
        const int* __restrict__ labels, float* __restrict__ ws) {
    // contiguous-per-XCD chunking (2080 % 8 == 0)
    const int grp = gridDim.x >> 3;
    const int tile = (blockIdx.x & 7) * grp + (blockIdx.x >> 3);
    // triangular decode: row-major over {(bi,bj): bj>=bi}
    int rem = tile, bi = 0;
    while (rem >= (NBT - bi)) { rem -= (NBT - bi); ++bi; }
    const int bj = bi + rem;

    const unsigned short* __restrict__ ebf = (const unsigned short*)(ws + 4096);
    float* __restrict__ pvals = ws + 64;

    __shared__ unsigned short As[2][64 * 64];  // 8 KB each, swizzled, NO pad
    __shared__ unsigned short Bs[2][64 * 64];
    __shared__ int lab_row[64], lab_col[64];
    __shared__ float red[4];

    const int t = threadIdx.x;
    const int w = t >> 6, l = t & 63;
    const int lq = l >> 4, lr = l & 15;  // quad, row-in-tile
    const int rowA0 = bi * 64, rowB0 = bj * 64;

    if (t < 64) lab_row[t] = labels[(rowA0 + t) >> 1];
    else if (t < 128) lab_col[t - 64] = labels[(rowB0 + t - 64) >> 1];

    // glds staging: lane l of wave w stages rows {w*8 + (l>>3), +32} with
    // swizzled global chunk cg = (l&7) ^ (l>>3); LDS side is lane-linear.
    const int l8 = l >> 3, l7 = l & 7;
    const int cg = l7 ^ l8;
    const unsigned short* gA0 = ebf + ((size_t)(rowA0 + w * 8 + l8) << 9) + cg * 8;
    const unsigned short* gB0 = ebf + ((size_t)(rowB0 + w * 8 + l8) << 9) + cg * 8;
    // wave-uniform LDS bases (elements): slot s = w*64 + l + j*256 -> s*8 elems
    const int lbase0 = w * 512;         // j=0
    const int lbase1 = w * 512 + 2048;  // j=1 (+32 rows)

    f32x4 acc[4] = {};

    // prologue: K-chunk 0 into buffer 0
    GLDS16(gA0, &As[0][lbase0]);
    GLDS16(gA0 + (32 << 9), &As[0][lbase1]);
    GLDS16(gB0, &Bs[0][lbase0]);
    GLDS16(gB0 + (32 << 9), &Bs[0][lbase1]);

    #pragma unroll
    for (int it = 0; it < 8; ++it) {
        const int cur = it & 1;
        // barrier: compiler drains vmcnt (chunk `cur` glds, issued last iter
        // and covered by last iter's compute) then s_barrier.
        __syncthreads();
        if (it < 7) {  // issue chunk it+1 -> other buffer; flies during compute
            const int nxt = cur ^ 1;
            const int k0 = (it + 1) * 64;
            GLDS16(gA0 + k0, &As[nxt][lbase0]);
            GLDS16(gA0 + (32 << 9) + k0, &As[nxt][lbase1]);
            GLDS16(gB0 + k0, &Bs[nxt][lbase0]);
            GLDS16(gB0 + (32 << 9) + k0, &Bs[nxt][lbase1]);
        }
        #pragma unroll
        for (int ks = 0; ks < 2; ++ks) {
            const int swz = ((ks * 4 + lq) ^ l7) * 8;  // swizzled k-chunk offset
            const bf16x8 af = *(const bf16x8*)&As[cur][(w * 16 + lr) * 64 + swz];
            bf16x8 bfr[4];
            #pragma unroll
            for (int nt = 0; nt < 4; ++nt)
                bfr[nt] = *(const bf16x8*)&Bs[cur][(nt * 16 + lr) * 64 + swz];
            #pragma unroll
            for (int nt = 0; nt < 4; ++nt)
                acc[nt] = __builtin_amdgcn_mfma_f32_16x16x32_bf16(
                    af, bfr[nt], acc[nt], 0, 0, 0);
        }
    }

    // Epilogue: C/D layout per 16x16 tile: row = lq*4+r, col = lr.
    float neg_local = 0.0f;
    #pragma unroll
    for (int nt = 0; nt < 4; ++nt) {
        const f32x4 a = acc[nt];
        #pragma unroll
        for (int r = 0; r < 4; ++r) {
            const int li = w * 16 + lq * 4 + r;
            const int lj = nt * 16 + lr;
            const int i = rowA0 + li;
            const int j = rowB0 + lj;
            const float S = a[r] * TEMP_INV;
            if (j > i) {
                if (lab_row[li] != lab_col[lj]) neg_local += __expf(S);
                if (!(i & 1) && j == i + 1) pvals[i >> 1] = S;
            }
        }
    }

    float s = neg_local;
    #pragma unroll
    for (int off = 32; off > 0; off >>= 1) s += __shfl_down(s, off, 64);
    if (l == 0) red[w] = s;
    __syncthreads();
    if (t == 0) atomicAdd(ws, red[0] + red[1] + red[2] + red[3]);
}

__global__ void infonce_loss_kernel(const float* __restrict__ ws,
                                    float* __restrict__ out, int npairs) {
    __shared__ float red[4];
    const float neg = ws[0];
    const float* __restrict__ p = ws + 64;
    float local = 0.0f;
    for (int k = threadIdx.x; k < npairs; k += 256) {
        const float pv = p[k];
        local += logf(__expf(pv) + neg) - pv;
    }
    float s = local;
    #pragma unroll
    for (int off = 32; off > 0; off >>= 1) s += __shfl_down(s, off, 64);
    if ((threadIdx.x & 63) == 0) red[threadIdx.x >> 6] = s;
    __syncthreads();
    if (threadIdx.x == 0)
        out[0] = (red[0] + red[1] + red[2] + red[3]) / (float)npairs;
}

extern "C" void kernel_launch(void* const* d_in, const int* in_sizes, int n_in,
                              void* d_out, int out_size, void* d_ws, size_t ws_size,
                              hipStream_t stream) {
    const float* emb = (const float*)d_in[0];
    const int* labels = (const int*)d_in[1];
    float* out = (float*)d_out;
    float* ws = (float*)d_ws;

    const int ntot = in_sizes[0] / D;  // 4096
    const int npairs = ntot / 2;       // 2048 positive pairs

    infonce_norm_cast_kernel<<<ntot / 4, 256, 0, stream>>>(emb, ws, ntot);
    infonce_sim_kernel<<<NBLK, 256, 0, stream>>>(labels, ws);
    infonce_loss_kernel<<<1, 256, 0, stream>>>(ws, out, npairs);
}

// Round 8
// 99.790 us; speedup vs baseline: 2.3649x; 1.0555x over previous
//
#include <hip/hip_runtime.h>
#include <math.h>

#define D 512
#define TEMP_INV 14.285714285714286f  // 1/0.07
#define NBT 64                         // 4096 / 64 tile grid dim
#define NBLK (NBT * (NBT + 1) / 2)     // 2080 upper-tri tiles
#define BK 128                         // K-chunk in elements (= bytes, fp8)

typedef int v8i __attribute__((ext_vector_type(8)));     // 32 fp8 elems
typedef float f32x16 __attribute__((ext_vector_type(16)));

// global->LDS direct DMA, 16 B per lane. LDS dest = wave-uniform base + lane*16.
#define GLDS16(g, l) __builtin_amdgcn_global_load_lds(                         \
    (const __attribute__((address_space(1))) unsigned int*)(g),                \
    (__attribute__((address_space(3))) unsigned int*)(l), 16, 0, 0)

// ws layout (float units):
//   [0]              neg_sum accumulator (float atomic)
//   [64 .. 64+2048)  p values (positive-pair logits)
//   [4096 .. )       efp8: normalized fp8(e4m3) matrix [4096][512] (2 MB)

// One wave per row: rsqrt(sum sq), scale, cvt to fp8 e4m3 (OCP), store packed.
__global__ void infonce_norm_cast_kernel(const float* __restrict__ emb,
                                         float* __restrict__ ws, int nrows) {
    if (blockIdx.x == 0 && threadIdx.x == 0) ws[0] = 0.0f;  // zero neg_sum
    unsigned int* __restrict__ ef = (unsigned int*)(ws + 4096);
    const int lane = threadIdx.x & 63;
    const int wave = threadIdx.x >> 6;
    const int row = blockIdx.x * 4 + wave;
    if (row >= nrows) return;
    const float* r = emb + (size_t)row * D;
    float4 v1 = *(const float4*)&r[lane * 4];
    float4 v2 = *(const float4*)&r[256 + lane * 4];
    float s = v1.x * v1.x + v1.y * v1.y + v1.z * v1.z + v1.w * v1.w
            + v2.x * v2.x + v2.y * v2.y + v2.z * v2.z + v2.w * v2.w;
    #pragma unroll
    for (int off = 32; off > 0; off >>= 1) s += __shfl_down(s, off, 64);
    const float rn = __shfl(rsqrtf(s), 0, 64);

    unsigned int p0 = __builtin_amdgcn_cvt_pk_fp8_f32(v1.x * rn, v1.y * rn, 0, false);
    p0 = __builtin_amdgcn_cvt_pk_fp8_f32(v1.z * rn, v1.w * rn, p0, true);
    unsigned int p1 = __builtin_amdgcn_cvt_pk_fp8_f32(v2.x * rn, v2.y * rn, 0, false);
    p1 = __builtin_amdgcn_cvt_pk_fp8_f32(v2.z * rn, v2.w * rn, p1, true);
    ef[(size_t)row * 128 + lane] = p0;        // bytes [lane*4, +4)
    ef[(size_t)row * 128 + 64 + lane] = p1;   // bytes [256 + lane*4, +4)
}

// Upper-triangular 64x64 tiles (2080 blocks -> 4 blocks/CU, 16 waves/CU),
// 256 threads (4 waves). Wave w -> 32x32 quadrant (wy,wx) via
// mfma_scale_f32_32x32x64_f8f6f4 (fp8 A/B, scales = 1.0). BK=128 -> only 4
// K-iters. glds staging into XOR-swizzled unpadded LDS (slot(row,c) =
// row*128 + (c ^ (row&7))*16): fragment reads are 4-lane same-address
// broadcasts over 8 slots spanning all 32 banks -> conflict-free. Rotating
// double buffer, ONE barrier/iter; glds for chunk it+1 issued post-barrier,
// its vmcnt drain covered by this iter's compute.
__global__ __launch_bounds__(256, 4) void infonce_sim_kernel(
        const int* __restrict__ labels, float* __restrict__ ws) {
    // contiguous-per-XCD chunking (2080 % 8 == 0)
    const int grp = gridDim.x >> 3;
    const int tile = (blockIdx.x & 7) * grp + (blockIdx.x >> 3);
    // triangular decode: row-major over {(bi,bj): bj>=bi}
    int rem = tile, bi = 0;
    while (rem >= (NBT - bi)) { rem -= (NBT - bi); ++bi; }
    const int bj = bi + rem;

    const unsigned char* __restrict__ efp8 = (const unsigned char*)(ws + 4096);
    float* __restrict__ pvals = ws + 64;

    __shared__ __align__(16) unsigned char As[2][64 * 128];  // 8 KB each
    __shared__ __align__(16) unsigned char Bs[2][64 * 128];
    __shared__ int lab_row[64], lab_col[64];
    __shared__ float red[4];

    const int t = threadIdx.x;
    const int w = t >> 6, l = t & 63;
    const int wy = w >> 1, wx = w & 1;
    const int ln = l & 31;   // row/col within 32x32 quadrant
    const int hi = l >> 5;   // k-half selector within one MFMA's K=64
    const int rowA0 = bi * 64, rowB0 = bj * 64;

    if (t < 64) lab_row[t] = labels[(rowA0 + t) >> 1];
    else if (t < 128) lab_col[t - 64] = labels[(rowB0 + t - 64) >> 1];

    // staging: wave w stages rows w*16 + j*8 + (l>>3), j=0,1, for A and B.
    // global 16B chunk cg = (l&7) ^ (l>>3) -> lane-linear LDS = swizzled slot.
    const int l8 = l >> 3, l7 = l & 7;
    const int cg = l7 ^ l8;
    const unsigned char* gA0 = efp8 + ((size_t)(rowA0 + w * 16 + l8) << 9) + cg * 16;
    const unsigned char* gA1 = gA0 + (8 << 9);  // +8 rows
    const unsigned char* gB0 = efp8 + ((size_t)(rowB0 + w * 16 + l8) << 9) + cg * 16;
    const unsigned char* gB1 = gB0 + (8 << 9);
    const int lb0 = w * 2048, lb1 = w * 2048 + 1024;  // wave-uniform LDS bases

    f32x16 acc = {};

    // prologue: K-chunk 0 into buffer 0
    GLDS16(gA0, &As[0][lb0]);
    GLDS16(gA1, &As[0][lb1]);
    GLDS16(gB0, &Bs[0][lb0]);
    GLDS16(gB1, &Bs[0][lb1]);

    const int ra = wy * 32 + ln;  // A row this lane contributes
    const int rb = wx * 32 + ln;  // B row (column of S)
    const int ma = ra & 7, mb = rb & 7;

    #pragma unroll
    for (int it = 0; it < 4; ++it) {
        const int cur = it & 1;
        __syncthreads();  // drains chunk-`cur` glds (covered by prev compute)
        if (it < 3) {     // issue chunk it+1 -> other buffer
            const int nxt = cur ^ 1;
            const int k0 = (it + 1) * BK;
            GLDS16(gA0 + k0, &As[nxt][lb0]);
            GLDS16(gA1 + k0, &As[nxt][lb1]);
            GLDS16(gB0 + k0, &Bs[nxt][lb0]);
            GLDS16(gB1 + k0, &Bs[nxt][lb1]);
        }
        #pragma unroll
        for (int ks = 0; ks < 2; ++ks) {
            const int c0 = hi * 2 + ks * 4;  // even 16B-chunk index of k-slice
            union { v8i v; uint4 q[2]; } ua, ub;
            ua.q[0] = *(const uint4*)&As[cur][ra * 128 + ((c0 ^ ma) << 4)];
            ua.q[1] = *(const uint4*)&As[cur][ra * 128 + (((c0 + 1) ^ ma) << 4)];
            ub.q[0] = *(const uint4*)&Bs[cur][rb * 128 + ((c0 ^ mb) << 4)];
            ub.q[1] = *(const uint4*)&Bs[cur][rb * 128 + (((c0 + 1) ^ mb) << 4)];
            acc = __builtin_amdgcn_mfma_scale_f32_32x32x64_f8f6f4(
                ua.v, ub.v, acc, 0, 0,             // fmtA=fp8, fmtB=fp8
                0, 0x7F7F7F7F, 0, 0x7F7F7F7F);     // scales = 1.0 (e8m0 127)
        }
    }

    // Epilogue: 32x32 C/D layout: col = lane&31, row = (reg&3)+8*(reg>>2)+4*(lane>>5).
    float neg_local = 0.0f;
    #pragma unroll
    for (int reg = 0; reg < 16; ++reg) {
        const int rrow = (reg & 3) + 8 * (reg >> 2) + 4 * hi;
        const int li = wy * 32 + rrow;
        const int lj = wx * 32 + ln;
        const int i = rowA0 + li;
        const int j = rowB0 + lj;
        const float S = acc[reg] * TEMP_INV;
        if (j > i) {
            if (lab_row[li] != lab_col[lj]) neg_local += __expf(S);
            if (!(i & 1) && j == i + 1) pvals[i >> 1] = S;
        }
    }

    float s = neg_local;
    #pragma unroll
    for (int off = 32; off > 0; off >>= 1) s += __shfl_down(s, off, 64);
    if (l == 0) red[w] = s;
    __syncthreads();
    if (t == 0) atomicAdd(ws, red[0] + red[1] + red[2] + red[3]);
}

__global__ void infonce_loss_kernel(const float* __restrict__ ws,
                                    float* __restrict__ out, int npairs) {
    __shared__ float red[4];
    const float neg = ws[0];
    const float* __restrict__ p = ws + 64;
    float local = 0.0f;
    for (int k = threadIdx.x; k < npairs; k += 256) {
        const float pv = p[k];
        local += logf(__expf(pv) + neg) - pv;
    }
    float s = local;
    #pragma unroll
    for (int off = 32; off > 0; off >>= 1) s += __shfl_down(s, off, 64);
    if ((threadIdx.x & 63) == 0) red[threadIdx.x >> 6] = s;
    __syncthreads();
    if (threadIdx.x == 0)
        out[0] = (red[0] + red[1] + red[2] + red[3]) / (float)npairs;
}

extern "C" void kernel_launch(void* const* d_in, const int* in_sizes, int n_in,
                              void* d_out, int out_size, void* d_ws, size_t ws_size,
                              hipStream_t stream) {
    const float* emb = (const float*)d_in[0];
    const int* labels = (const int*)d_in[1];
    float* out = (float*)d_out;
    float* ws = (float*)d_ws;

    const int ntot = in_sizes[0] / D;  // 4096
    const int npairs = ntot / 2;       // 2048 positive pairs

    infonce_norm_cast_kernel<<<ntot / 4, 256, 0, stream>>>(emb, ws, ntot);
    infonce_sim_kernel<<<NBLK, 256, 0, stream>>>(labels, ws);
    infonce_loss_kernel<<<1, 256, 0, stream>>>(ws, out, npairs);
}

// Round 9
// 98.058 us; speedup vs baseline: 2.4067x; 1.0177x over previous
//
#include <hip/hip_runtime.h>
#include <math.h>

#define D 512
#define TEMP_INV 14.285714285714286f  // 1/0.07
#define NBT 64                         // 4096 / 64 tile grid dim
#define NBLK (NBT * (NBT + 1) / 2)     // 2080 upper-tri tiles

typedef int v8i __attribute__((ext_vector_type(8)));     // 32 fp8 elems
typedef float f32x16 __attribute__((ext_vector_type(16)));

// global->LDS direct DMA, 16 B per lane. LDS dest = wave-uniform base + lane*16.
#define GLDS16(g, l) __builtin_amdgcn_global_load_lds(                         \
    (const __attribute__((address_space(1))) unsigned int*)(g),                \
    (__attribute__((address_space(3))) unsigned int*)(l), 16, 0, 0)

// ws layout (float units):
//   [0]              neg_sum accumulator (float atomic)
//   [64 .. 64+2048)  p values (positive-pair logits)
//   [4096 .. )       efp8: normalized fp8(e4m3) matrix [4096][512] (2 MB)

// One wave per row: rsqrt(sum sq), scale, cvt to fp8 e4m3 (OCP), store packed.
__global__ void infonce_norm_cast_kernel(const float* __restrict__ emb,
                                         float* __restrict__ ws, int nrows) {
    if (blockIdx.x == 0 && threadIdx.x == 0) ws[0] = 0.0f;  // zero neg_sum
    unsigned int* __restrict__ ef = (unsigned int*)(ws + 4096);
    const int lane = threadIdx.x & 63;
    const int wave = threadIdx.x >> 6;
    const int row = blockIdx.x * 4 + wave;
    if (row >= nrows) return;
    const float* r = emb + (size_t)row * D;
    float4 v1 = *(const float4*)&r[lane * 4];
    float4 v2 = *(const float4*)&r[256 + lane * 4];
    float s = v1.x * v1.x + v1.y * v1.y + v1.z * v1.z + v1.w * v1.w
            + v2.x * v2.x + v2.y * v2.y + v2.z * v2.z + v2.w * v2.w;
    #pragma unroll
    for (int off = 32; off > 0; off >>= 1) s += __shfl_down(s, off, 64);
    const float rn = __shfl(rsqrtf(s), 0, 64);

    unsigned int p0 = __builtin_amdgcn_cvt_pk_fp8_f32(v1.x * rn, v1.y * rn, 0, false);
    p0 = __builtin_amdgcn_cvt_pk_fp8_f32(v1.z * rn, v1.w * rn, p0, true);
    unsigned int p1 = __builtin_amdgcn_cvt_pk_fp8_f32(v2.x * rn, v2.y * rn, 0, false);
    p1 = __builtin_amdgcn_cvt_pk_fp8_f32(v2.z * rn, v2.w * rn, p1, true);
    ef[(size_t)row * 128 + lane] = p0;        // bytes [lane*4, +4)
    ef[(size_t)row * 128 + 64 + lane] = p1;   // bytes [256 + lane*4, +4)
}

// Upper-triangular 64x64 tiles (2080 blocks), 256 threads (4 waves). fp8:
// both FULL panels (64 rows x 512 B = 32 KB each) fit in LDS -> single-shot
// staging: 16 glds/wave issued back-to-back, ONE vmcnt drain at ONE barrier,
// then 8 chained mfma_scale_f32_32x32x64_f8f6f4 per wave (K=512), epilogue.
// One latency exposure per block instead of 4 (R8) / 8 (R3).
// Full-row XOR swizzle: chunk c of row r stored at slot (c&~7)|((c^r)&7):
// glds stays coalesced (8-lane groups read one permuted 128 B line) and
// fragment reads are conflict-free (8 consecutive rows span all 32 banks).
__global__ __launch_bounds__(256, 2) void infonce_sim_kernel(
        const int* __restrict__ labels, float* __restrict__ ws) {
    // contiguous-per-XCD chunking (2080 % 8 == 0)
    const int grp = gridDim.x >> 3;
    const int tile = (blockIdx.x & 7) * grp + (blockIdx.x >> 3);
    // triangular decode: row-major over {(bi,bj): bj>=bi}
    int rem = tile, bi = 0;
    while (rem >= (NBT - bi)) { rem -= (NBT - bi); ++bi; }
    const int bj = bi + rem;

    const unsigned char* __restrict__ efp8 = (const unsigned char*)(ws + 4096);
    float* __restrict__ pvals = ws + 64;

    __shared__ __align__(16) unsigned char As[64 * 512];  // 32 KB
    __shared__ __align__(16) unsigned char Bs[64 * 512];  // 32 KB
    __shared__ int lab_row[64], lab_col[64];
    __shared__ float red[4];

    const int t = threadIdx.x;
    const int w = t >> 6, l = t & 63;
    const int wy = w >> 1, wx = w & 1;
    const int ln = l & 31;   // row/col within 32x32 quadrant
    const int hi = l >> 5;   // k-half selector within one MFMA's K=64
    const int rowA0 = bi * 64, rowB0 = bj * 64;

    if (t < 64) lab_row[t] = labels[(rowA0 + t) >> 1];
    else if (t < 128) lab_col[t - 64] = labels[(rowB0 + t - 64) >> 1];

    // ---- single-shot staging: wave w stages rows [w*16, w*16+16) of A and B.
    // instr s covers 2 rows (32 lanes = 512 B = one row each). Lane l:
    // r = w*16 + s*2 + (l>>5), chunk-slot cl = l&31, global chunk
    // c = (cl & 24) | ((cl ^ r) & 7)  (inverse of the XOR swizzle).
    {
        const int rl = l >> 5, cl = l & 31;
        #pragma unroll
        for (int s = 0; s < 8; ++s) {
            const int r = w * 16 + s * 2 + rl;
            const int c = (cl & 24) | ((cl ^ r) & 7);
            const size_t gofs = ((size_t)r << 9) + c * 16;
            const int lbase = (w * 16 + s * 2) * 512;  // wave-uniform
            GLDS16(efp8 + (((size_t)rowA0) << 9) + gofs, &As[lbase]);
            GLDS16(efp8 + (((size_t)rowB0) << 9) + gofs, &Bs[lbase]);
        }
    }

    f32x16 acc = {};
    const int ra = wy * 32 + ln;  // A row this lane contributes
    const int rb = wx * 32 + ln;  // B row (column of S)

    __syncthreads();  // single vmcnt(0) drain: all 16 glds/wave in flight

    #pragma unroll
    for (int kk = 0; kk < 8; ++kk) {
        const int c0 = kk * 4 + hi * 2;
        const int sa0 = (c0 & 24) | ((c0 ^ ra) & 7);
        const int sa1 = ((c0 + 1) & 24) | (((c0 + 1) ^ ra) & 7);
        const int sb0 = (c0 & 24) | ((c0 ^ rb) & 7);
        const int sb1 = ((c0 + 1) & 24) | (((c0 + 1) ^ rb) & 7);
        union { v8i v; uint4 q[2]; } ua, ub;
        ua.q[0] = *(const uint4*)&As[ra * 512 + (sa0 << 4)];
        ua.q[1] = *(const uint4*)&As[ra * 512 + (sa1 << 4)];
        ub.q[0] = *(const uint4*)&Bs[rb * 512 + (sb0 << 4)];
        ub.q[1] = *(const uint4*)&Bs[rb * 512 + (sb1 << 4)];
        acc = __builtin_amdgcn_mfma_scale_f32_32x32x64_f8f6f4(
            ua.v, ub.v, acc, 0, 0,             // fmtA=fp8, fmtB=fp8
            0, 0x7F7F7F7F, 0, 0x7F7F7F7F);     // scales = 1.0 (e8m0 127)
    }

    // Epilogue: 32x32 C/D layout: col = lane&31, row = (reg&3)+8*(reg>>2)+4*(lane>>5).
    float neg_local = 0.0f;
    #pragma unroll
    for (int reg = 0; reg < 16; ++reg) {
        const int rrow = (reg & 3) + 8 * (reg >> 2) + 4 * hi;
        const int li = wy * 32 + rrow;
        const int lj = wx * 32 + ln;
        const int i = rowA0 + li;
        const int j = rowB0 + lj;
        const float S = acc[reg] * TEMP_INV;
        if (j > i) {
            if (lab_row[li] != lab_col[lj]) neg_local += __expf(S);
            if (!(i & 1) && j == i + 1) pvals[i >> 1] = S;
        }
    }

    float s = neg_local;
    #pragma unroll
    for (int off = 32; off > 0; off >>= 1) s += __shfl_down(s, off, 64);
    if (l == 0) red[w] = s;
    __syncthreads();
    if (t == 0) atomicAdd(ws, red[0] + red[1] + red[2] + red[3]);
}

__global__ void infonce_loss_kernel(const float* __restrict__ ws,
                                    float* __restrict__ out, int npairs) {
    __shared__ float red[4];
    const float neg = ws[0];
    const float* __restrict__ p = ws + 64;
    float local = 0.0f;
    for (int k = threadIdx.x; k < npairs; k += 256) {
        const float pv = p[k];
        local += logf(__expf(pv) + neg) - pv;
    }
    float s = local;
    #pragma unroll
    for (int off = 32; off > 0; off >>= 1) s += __shfl_down(s, off, 64);
    if ((threadIdx.x & 63) == 0) red[threadIdx.x >> 6] = s;
    __syncthreads();
    if (threadIdx.x == 0)
        out[0] = (red[0] + red[1] + red[2] + red[3]) / (float)npairs;
}

extern "C" void kernel_launch(void* const* d_in, const int* in_sizes, int n_in,
                              void* d_out, int out_size, void* d_ws, size_t ws_size,
                              hipStream_t stream) {
    const float* emb = (const float*)d_in[0];
    const int* labels = (const int*)d_in[1];
    float* out = (float*)d_out;
    float* ws = (float*)d_ws;

    const int ntot = in_sizes[0] / D;  // 4096
    const int npairs = ntot / 2;       // 2048 positive pairs

    infonce_norm_cast_kernel<<<ntot / 4, 256, 0, stream>>>(emb, ws, ntot);
    infonce_sim_kernel<<<NBLK, 256, 0, stream>>>(labels, ws);
    infonce_loss_kernel<<<1, 256, 0, stream>>>(ws, out, npairs);
}

// Round 10
// 90.630 us; speedup vs baseline: 2.6039x; 1.0820x over previous
//
#include <hip/hip_runtime.h>
#include <math.h>

#define D 512
#define TEMP_INV 14.285714285714286f  // 1/0.07
#define NBT 32                         // 4096 / 128 tile grid dim
#define NBLK (NBT * (NBT + 1) / 2)     // 528 upper-tri tiles

typedef int v8i __attribute__((ext_vector_type(8)));     // 32 fp8 elems
typedef float f32x16 __attribute__((ext_vector_type(16)));

// global->LDS direct DMA, 16 B per lane. LDS dest = wave-uniform base + lane*16.
#define GLDS16(g, l) __builtin_amdgcn_global_load_lds(                         \
    (const __attribute__((address_space(1))) unsigned int*)(g),                \
    (__attribute__((address_space(3))) unsigned int*)(l), 16, 0, 0)

// ws layout (float units):
//   [0]              neg_sum accumulator (float atomic)
//   [64 .. 64+2048)  p values (positive-pair logits)
//   [4096 .. )       efp8: normalized fp8(e4m3) matrix [4096][512] (2 MB)

// One wave per row: rsqrt(sum sq), scale, cvt to fp8 e4m3 (OCP), store packed.
__global__ void infonce_norm_cast_kernel(const float* __restrict__ emb,
                                         float* __restrict__ ws, int nrows) {
    if (blockIdx.x == 0 && threadIdx.x == 0) ws[0] = 0.0f;  // zero neg_sum
    unsigned int* __restrict__ ef = (unsigned int*)(ws + 4096);
    const int lane = threadIdx.x & 63;
    const int wave = threadIdx.x >> 6;
    const int row = blockIdx.x * 4 + wave;
    if (row >= nrows) return;
    const float* r = emb + (size_t)row * D;
    float4 v1 = *(const float4*)&r[lane * 4];
    float4 v2 = *(const float4*)&r[256 + lane * 4];
    float s = v1.x * v1.x + v1.y * v1.y + v1.z * v1.z + v1.w * v1.w
            + v2.x * v2.x + v2.y * v2.y + v2.z * v2.z + v2.w * v2.w;
    #pragma unroll
    for (int off = 32; off > 0; off >>= 1) s += __shfl_down(s, off, 64);
    const float rn = __shfl(rsqrtf(s), 0, 64);

    unsigned int p0 = __builtin_amdgcn_cvt_pk_fp8_f32(v1.x * rn, v1.y * rn, 0, false);
    p0 = __builtin_amdgcn_cvt_pk_fp8_f32(v1.z * rn, v1.w * rn, p0, true);
    unsigned int p1 = __builtin_amdgcn_cvt_pk_fp8_f32(v2.x * rn, v2.y * rn, 0, false);
    p1 = __builtin_amdgcn_cvt_pk_fp8_f32(v2.z * rn, v2.w * rn, p1, true);
    ef[(size_t)row * 128 + lane] = p0;        // bytes [lane*4, +4)
    ef[(size_t)row * 128 + 64 + lane] = p1;   // bytes [256 + lane*4, +4)
}

// Upper-triangular 128x128 tiles (528 blocks), 256 threads (4 waves). fp8:
// both FULL panels (128 rows x 512 B = 64 KB each) fit in LDS (132 KB total,
// 1 block/CU). Single-shot staging: 32 glds/wave back-to-back, ONE vmcnt
// drain at ONE barrier, then 32 mfma_scale_f32_32x32x64_f8f6f4 per wave
// (wave w -> 64x64 quadrant (wy,wx) as 2x2 sub-tiles of 32x32, K=512).
// Halves global panel traffic vs 64-tiles (68 MB vs 133 MB) and cuts
// blocks/atomics/drain-exposures 4x — attacks the poison-writeback
// contention floor. Full-row XOR swizzle: chunk c of row r at slot
// (c&~7)|((c^r)&7): glds coalesced, fragment reads conflict-free.
__global__ __launch_bounds__(256, 1) void infonce_sim_kernel(
        const int* __restrict__ labels, float* __restrict__ ws) {
    // contiguous-per-XCD chunking (528 % 8 == 0)
    const int grp = gridDim.x >> 3;
    const int tile = (blockIdx.x & 7) * grp + (blockIdx.x >> 3);
    // triangular decode: row-major over {(bi,bj): bj>=bi}
    int rem = tile, bi = 0;
    while (rem >= (NBT - bi)) { rem -= (NBT - bi); ++bi; }
    const int bj = bi + rem;

    const unsigned char* __restrict__ efp8 = (const unsigned char*)(ws + 4096);
    float* __restrict__ pvals = ws + 64;

    __shared__ __align__(16) unsigned char As[128 * 512];  // 64 KB
    __shared__ __align__(16) unsigned char Bs[128 * 512];  // 64 KB
    __shared__ int lab_row[128], lab_col[128];
    __shared__ float red[4];

    const int t = threadIdx.x;
    const int w = t >> 6, l = t & 63;
    const int wy = w >> 1, wx = w & 1;
    const int ln = l & 31;   // row/col within a 32x32 sub-tile
    const int hi = l >> 5;   // k-half selector within one MFMA's K=64
    const int rowA0 = bi * 128, rowB0 = bj * 128;

    if (t < 128) lab_row[t] = labels[(rowA0 + t) >> 1];
    else lab_col[t - 128] = labels[(rowB0 + t - 128) >> 1];

    // ---- single-shot staging: wave w stages rows [w*32, w*32+32) of A and B.
    // glds s covers 2 rows (64 lanes x 16 B = 1 KB). Lane l: r = w*32 + s*2
    // + (l>>5), slot cl = l&31, global chunk c = (cl&24)|((cl^r)&7).
    {
        const int rl = l >> 5, cl = l & 31;
        const unsigned char* gA = efp8 + ((size_t)rowA0 << 9);
        const unsigned char* gB = efp8 + ((size_t)rowB0 << 9);
        #pragma unroll
        for (int s = 0; s < 16; ++s) {
            const int r = w * 32 + s * 2 + rl;
            const int c = (cl & 24) | ((cl ^ r) & 7);
            const size_t gofs = ((size_t)r << 9) + c * 16;
            const int lbase = (w * 32 + s * 2) * 512;  // wave-uniform
            GLDS16(gA + gofs, &As[lbase]);
            GLDS16(gB + gofs, &Bs[lbase]);
        }
    }

    f32x16 acc[4] = {};  // [ma*2+nb]

    __syncthreads();  // single vmcnt(0) drain: 32 glds/wave in flight

    #pragma unroll
    for (int kk = 0; kk < 8; ++kk) {
        const int c0 = kk * 4 + hi * 2, c1 = c0 + 1;
        union { v8i v; uint4 q[2]; } ua[2], ub[2];
        #pragma unroll
        for (int ma = 0; ma < 2; ++ma) {
            const int ra = wy * 64 + ma * 32 + ln;
            ua[ma].q[0] = *(const uint4*)&As[ra * 512 + (((c0 & 24) | ((c0 ^ ra) & 7)) << 4)];
            ua[ma].q[1] = *(const uint4*)&As[ra * 512 + (((c1 & 24) | ((c1 ^ ra) & 7)) << 4)];
        }
        #pragma unroll
        for (int nb = 0; nb < 2; ++nb) {
            const int rb = wx * 64 + nb * 32 + ln;
            ub[nb].q[0] = *(const uint4*)&Bs[rb * 512 + (((c0 & 24) | ((c0 ^ rb) & 7)) << 4)];
            ub[nb].q[1] = *(const uint4*)&Bs[rb * 512 + (((c1 & 24) | ((c1 ^ rb) & 7)) << 4)];
        }
        #pragma unroll
        for (int ma = 0; ma < 2; ++ma)
            #pragma unroll
            for (int nb = 0; nb < 2; ++nb)
                acc[ma * 2 + nb] = __builtin_amdgcn_mfma_scale_f32_32x32x64_f8f6f4(
                    ua[ma].v, ub[nb].v, acc[ma * 2 + nb], 0, 0,
                    0, 0x7F7F7F7F, 0, 0x7F7F7F7F);  // fp8/fp8, scales = 1.0
    }

    // Epilogue: 32x32 C/D layout: col = lane&31, row = (reg&3)+8*(reg>>2)+4*(lane>>5).
    float neg_local = 0.0f;
    #pragma unroll
    for (int ma = 0; ma < 2; ++ma) {
        #pragma unroll
        for (int nb = 0; nb < 2; ++nb) {
            const f32x16 a = acc[ma * 2 + nb];
            #pragma unroll
            for (int reg = 0; reg < 16; ++reg) {
                const int rrow = (reg & 3) + 8 * (reg >> 2) + 4 * hi;
                const int li = wy * 64 + ma * 32 + rrow;
                const int lj = wx * 64 + nb * 32 + ln;
                const int i = rowA0 + li;
                const int j = rowB0 + lj;
                const float S = a[reg] * TEMP_INV;
                if (j > i) {
                    if (lab_row[li] != lab_col[lj]) neg_local += __expf(S);
                    if (!(i & 1) && j == i + 1) pvals[i >> 1] = S;
                }
            }
        }
    }

    float s = neg_local;
    #pragma unroll
    for (int off = 32; off > 0; off >>= 1) s += __shfl_down(s, off, 64);
    if (l == 0) red[w] = s;
    __syncthreads();
    if (t == 0) atomicAdd(ws, red[0] + red[1] + red[2] + red[3]);
}

__global__ void infonce_loss_kernel(const float* __restrict__ ws,
                                    float* __restrict__ out, int npairs) {
    __shared__ float red[4];
    const float neg = ws[0];
    const float* __restrict__ p = ws + 64;
    float local = 0.0f;
    for (int k = threadIdx.x; k < npairs; k += 256) {
        const float pv = p[k];
        local += logf(__expf(pv) + neg) - pv;
    }
    float s = local;
    #pragma unroll
    for (int off = 32; off > 0; off >>= 1) s += __shfl_down(s, off, 64);
    if ((threadIdx.x & 63) == 0) red[threadIdx.x >> 6] = s;
    __syncthreads();
    if (threadIdx.x == 0)
        out[0] = (red[0] + red[1] + red[2] + red[3]) / (float)npairs;
}

extern "C" void kernel_launch(void* const* d_in, const int* in_sizes, int n_in,
                              void* d_out, int out_size, void* d_ws, size_t ws_size,
                              hipStream_t stream) {
    const float* emb = (const float*)d_in[0];
    const int* labels = (const int*)d_in[1];
    float* out = (float*)d_out;
    float* ws = (float*)d_ws;

    const int ntot = in_sizes[0] / D;  // 4096
    const int npairs = ntot / 2;       // 2048 positive pairs

    infonce_norm_cast_kernel<<<ntot / 4, 256, 0, stream>>>(emb, ws, ntot);
    infonce_sim_kernel<<<NBLK, 256, 0, stream>>>(labels, ws);
    infonce_loss_kernel<<<1, 256, 0, stream>>>(ws, out, npairs);
}